// Round 1
// baseline (12.886 us; speedup 1.0000x reference)
//
#include <hip/hip_runtime.h>
#include <math.h>

#define IMG_S 256
#define FMAX 256

// Exact-order IEEE f32 helpers (never FMA-contracted)
#define FADD(a,b) __fadd_rn((a),(b))
#define FSUB(a,b) __fsub_rn((a),(b))
#define FMUL(a,b) __fmul_rn((a),(b))
#define FDIV(a,b) __fdiv_rn((a),(b))

__global__ __launch_bounds__(256) void raster_kernel(
    const float* __restrict__ faces,   // [F,3,3]
    const float* __restrict__ tex,     // [F,4,4,4,3]
    float* __restrict__ out,           // [3,S,S]
    int F)
{
    __shared__ float s_a0[FMAX], s_b0[FMAX], s_a1[FMAX], s_b1[FMAX];
    __shared__ float s_x2[FMAX], s_y2[FMAX];
    __shared__ float s_z0[FMAX], s_z1[FMAX], s_z2[FMAX];
    __shared__ float s_den[FMAX];
    __shared__ int   s_fid[FMAX];
    __shared__ int   s_cnt[4];

    const int tid = threadIdx.x;
    const int lane = tid & 63;
    const int wid  = tid >> 6;

    // tile: 64 wide (x) x 4 tall (y)
    const int tile_x = blockIdx.x & 3;
    const int tile_y = blockIdx.x >> 2;
    const int col0 = tile_x * 64;
    const int row0 = tile_y * 4;

    // tile NDC pixel-center bounds
    const float px_min = (float)(2*col0        + 1 - IMG_S) / (float)IMG_S;
    const float px_max = (float)(2*(col0+63)   + 1 - IMG_S) / (float)IMG_S;
    const float py_max = -(float)(2*row0       + 1 - IMG_S) / (float)IMG_S;
    const float py_min = -(float)(2*(row0+3)   + 1 - IMG_S) / (float)IMG_S;
    const float MARGIN = 1e-3f;

    // ---- Phase A: cull faces vs tile, ordered compaction into LDS ----
    bool keep = false;
    float x0=0,y0=0,z0=0,x1=0,y1=0,z1=0,x2=0,y2=0,z2=0,den=0.f;
    if (tid < F) {
        const float* fp = faces + (size_t)tid * 9;
        x0=fp[0]; y0=fp[1]; z0=fp[2];
        x1=fp[3]; y1=fp[4]; z1=fp[5];
        x2=fp[6]; y2=fp[7]; z2=fp[8];
        // denom exactly as reference: (y1-y2)*(x0-x2) + (x2-x1)*(y0-y2)
        den = FADD(FMUL(FSUB(y1,y2), FSUB(x0,x2)),
                   FMUL(FSUB(x2,x1), FSUB(y0,y2)));
        float bxmin = fminf(fminf(x0,x1),x2), bxmax = fmaxf(fmaxf(x0,x1),x2);
        float bymin = fminf(fminf(y0,y1),y2), bymax = fmaxf(fmaxf(y0,y1),y2);
        keep = (bxmin - MARGIN <= px_max) && (bxmax + MARGIN >= px_min)
            && (bymin - MARGIN <= py_max) && (bymax + MARGIN >= py_min);
        // degenerate-denominator safety: never cull those
        keep = keep || (fabsf(den) < 1e-9f);
    }
    unsigned long long m = __ballot(keep);
    if (lane == 0) s_cnt[wid] = (int)__popcll(m);
    __syncthreads();
    int base = 0;
    #pragma unroll
    for (int w = 0; w < 4; ++w) if (w < wid) base += s_cnt[w];
    if (keep) {
        int pos = base + (int)__popcll(m & ((1ull << lane) - 1ull));
        float dn = den;
        if (fabsf(dn) < 1e-12f) dn = 1e-12f;   // reference's where() replacement
        s_a0[pos] = FSUB(y1,y2);
        s_b0[pos] = FSUB(x2,x1);
        s_a1[pos] = FSUB(y2,y0);
        s_b1[pos] = FSUB(x0,x2);
        s_x2[pos] = x2; s_y2[pos] = y2;
        s_z0[pos] = z0; s_z1[pos] = z1; s_z2[pos] = z2;
        s_den[pos] = dn;
        s_fid[pos] = tid;
    }
    __syncthreads();
    const int nk = s_cnt[0] + s_cnt[1] + s_cnt[2] + s_cnt[3];

    // ---- Phase B: rasterize one pixel per thread ----
    const int col = col0 + lane;
    const int row = row0 + wid;
    const float px = (float)(2*col + 1 - IMG_S) / (float)IMG_S;
    const float py = -(float)(2*row + 1 - IMG_S) / (float)IMG_S;

    float bestz = INFINITY;
    int   besti = -1;
    float bc0=0.f, bc1=0.f, bc2=0.f, bzp=0.f;

    for (int i = 0; i < nk; ++i) {
        float dx2 = FSUB(px, s_x2[i]);
        float dy2 = FSUB(py, s_y2[i]);
        float dn  = s_den[i];
        float w0 = FDIV(FADD(FMUL(s_a0[i],dx2), FMUL(s_b0[i],dy2)), dn);
        float w1 = FDIV(FADD(FMUL(s_a1[i],dx2), FMUL(s_b1[i],dy2)), dn);
        float w2 = FSUB(FSUB(1.0f, w0), w1);
        if (!(w0 >= 0.0f && w1 >= 0.0f && w2 >= 0.0f)) continue;

        float cc0 = fminf(fmaxf(w0, 0.0f), 1.0f);
        float cc1 = fminf(fmaxf(w1, 0.0f), 1.0f);
        float cc2 = fminf(fmaxf(w2, 0.0f), 1.0f);
        float ss  = fmaxf(FADD(FADD(cc0,cc1),cc2), 1e-12f);
        cc0 = FDIV(cc0, ss); cc1 = FDIV(cc1, ss); cc2 = FDIV(cc2, ss);

        float iz = FADD(FADD(FDIV(cc0, s_z0[i]), FDIV(cc1, s_z1[i])), FDIV(cc2, s_z2[i]));
        float t  = FADD(iz, 1e-30f);
        float sg = (t > 0.0f) ? 1.0f : ((t < 0.0f) ? -1.0f : 0.0f);
        float zp = FMUL(FDIV(1.0f, fmaxf(fabsf(iz), 1e-12f)), sg);

        if (zp > 0.1f && zp < 100.0f && zp < bestz) {
            bestz = zp; besti = i;
            bc0 = cc0; bc1 = cc1; bc2 = cc2; bzp = zp;
        }
    }

    float pr = 0.0f, pg = 0.0f, pb = 0.0f;
    if (besti >= 0) {
        const int i = besti;
        float zs[3] = { s_z0[i], s_z1[i], s_z2[i] };
        float wc[3] = { bc0, bc1, bc2 };
        int   ti0[3];
        float fr[3];
        #pragma unroll
        for (int k = 0; k < 3; ++k) {
            // tif = (wc * 3) * (zp / zw), clipped to [0, 3 - 0.001]
            float v = FMUL(FMUL(wc[k], 3.0f), FDIV(bzp, zs[k]));
            v = fminf(fmaxf(v, 0.0f), 2.999f);
            float fl = floorf(v);
            ti0[k] = (int)fl;
            fr[k]  = FSUB(v, fl);
        }
        const float* tp = tex + (size_t)s_fid[i] * 192;   // 4*4*4*3
        #pragma unroll
        for (int corner = 0; corner < 8; ++corner) {
            float w = 1.0f;
            int idx[3];
            #pragma unroll
            for (int k = 0; k < 3; ++k) {
                int bit = (corner >> k) & 1;
                w = FMUL(w, bit ? fr[k] : FSUB(1.0f, fr[k]));
                int id = ti0[k] + bit; if (id > 3) id = 3;
                idx[k] = id;
            }
            const float* tv = tp + (size_t)(((idx[0]*4 + idx[1])*4 + idx[2])*3);
            pr = FADD(pr, FMUL(w, tv[0]));
            pg = FADD(pg, FMUL(w, tv[1]));
            pb = FADD(pb, FMUL(w, tv[2]));
        }
    }

    const int p = row * IMG_S + col;
    out[p]                       = pr;
    out[IMG_S*IMG_S + p]         = pg;
    out[2*IMG_S*IMG_S + p]       = pb;
}

extern "C" void kernel_launch(void* const* d_in, const int* in_sizes, int n_in,
                              void* d_out, int out_size, void* d_ws, size_t ws_size,
                              hipStream_t stream) {
    const float* faces = (const float*)d_in[0];   // [1,F,3,3] f32
    const float* tex   = (const float*)d_in[1];   // [1,F,4,4,4,3] f32
    float* out = (float*)d_out;                   // [1,3,256,256] f32
    const int F = in_sizes[0] / 9;                // B=1

    const int grid = (IMG_S / 64) * (IMG_S / 4);  // 4 * 64 = 256 blocks
    raster_kernel<<<grid, 256, 0, stream>>>(faces, tex, out, F);
}

// Round 2
// 10.916 us; speedup vs baseline: 1.1804x; 1.1804x over previous
//
#include <hip/hip_runtime.h>
#include <math.h>

#define IMG_S 256
#define FCAP 512

// Exact-order IEEE f32 helpers (never FMA-contracted)
#define FADD(a,b) __fadd_rn((a),(b))
#define FSUB(a,b) __fsub_rn((a),(b))
#define FMUL(a,b) __fmul_rn((a),(b))
#define FDIV(a,b) __fdiv_rn((a),(b))

__global__ __launch_bounds__(256) void raster_kernel(
    const float* __restrict__ faces,   // [F,3,3]
    const float* __restrict__ tex,     // [F,4,4,4,3]
    float* __restrict__ out,           // [3,S,S]
    int F)
{
    // packed per-face data:
    //   A = (a0, b0, a1, b1)        a0=y1-y2 b0=x2-x1 a1=y2-y0 b1=x0-x2
    //   B = (x2, y2, den, z0)
    //   C = (z1, z2, fid_bits, 0)
    __shared__ float4 s_A[FCAP], s_B[FCAP], s_C[FCAP];
    __shared__ int    s_cnt[4];

    const int tid  = threadIdx.x;
    const int lane = tid & 63;
    const int wid  = tid >> 6;

    // 16x16 pixel tile per block
    const int tile_x = blockIdx.x & 15;
    const int tile_y = blockIdx.x >> 4;
    const int col0 = tile_x * 16;
    const int row0 = tile_y * 16;

    // tile NDC pixel-center bounds
    const float px_min = (float)(2*col0        + 1 - IMG_S) / (float)IMG_S;
    const float px_max = (float)(2*(col0+15)   + 1 - IMG_S) / (float)IMG_S;
    const float py_max = -(float)(2*row0       + 1 - IMG_S) / (float)IMG_S;
    const float py_min = -(float)(2*(row0+15)  + 1 - IMG_S) / (float)IMG_S;
    const float MARGIN = 1e-3f;

    // ---- Phase A: cull faces vs tile, ordered compaction into LDS ----
    int nk = 0;
    for (int f0 = 0; f0 < F; f0 += 256) {
        const int f = f0 + tid;
        bool keep = false;
        float x0=0,y0=0,z0=0,x1=0,y1=0,z1=0,x2=0,y2=0,z2=0,den=0.f;
        if (f < F) {
            const float* fp = faces + (size_t)f * 9;
            x0=fp[0]; y0=fp[1]; z0=fp[2];
            x1=fp[3]; y1=fp[4]; z1=fp[5];
            x2=fp[6]; y2=fp[7]; z2=fp[8];
            den = FADD(FMUL(FSUB(y1,y2), FSUB(x0,x2)),
                       FMUL(FSUB(x2,x1), FSUB(y0,y2)));
            float bxmin = fminf(fminf(x0,x1),x2), bxmax = fmaxf(fmaxf(x0,x1),x2);
            float bymin = fminf(fminf(y0,y1),y2), bymax = fmaxf(fmaxf(y0,y1),y2);
            keep = (bxmin - MARGIN <= px_max) && (bxmax + MARGIN >= px_min)
                && (bymin - MARGIN <= py_max) && (bymax + MARGIN >= py_min);
            keep = keep || (fabsf(den) < 1e-9f);   // degenerate safety
        }
        unsigned long long m = __ballot(keep);
        if (lane == 0) s_cnt[wid] = (int)__popcll(m);
        __syncthreads();
        int base = nk;
        #pragma unroll
        for (int w = 0; w < 4; ++w) if (w < wid) base += s_cnt[w];
        if (keep) {
            int pos = base + (int)__popcll(m & ((1ull << lane) - 1ull));
            if (pos < FCAP) {
                float dn = den;
                if (fabsf(dn) < 1e-12f) dn = 1e-12f;  // reference's where()
                s_A[pos] = make_float4(FSUB(y1,y2), FSUB(x2,x1), FSUB(y2,y0), FSUB(x0,x2));
                s_B[pos] = make_float4(x2, y2, dn, z0);
                s_C[pos] = make_float4(z1, z2, __int_as_float(f), 0.0f);
            }
        }
        nk += s_cnt[0] + s_cnt[1] + s_cnt[2] + s_cnt[3];
        __syncthreads();   // s_cnt reuse + LDS visibility
    }
    if (nk > FCAP) nk = FCAP;

    // ---- Phase B: rasterize one pixel per thread ----
    const int col = col0 + (tid & 15);
    const int row = row0 + (tid >> 4);
    const float px = (float)(2*col + 1 - IMG_S) / (float)IMG_S;
    const float py = -(float)(2*row + 1 - IMG_S) / (float)IMG_S;

    float bestz = INFINITY;
    int   besti = -1;
    float bc0=0.f, bc1=0.f, bc2=0.f, bzp=0.f;

    for (int i = 0; i < nk; ++i) {
        const float4 va = s_A[i];
        const float4 vb = s_B[i];
        const float dx2 = FSUB(px, vb.x);
        const float dy2 = FSUB(py, vb.y);
        const float num0 = FADD(FMUL(va.x,dx2), FMUL(va.y,dy2));
        const float num1 = FADD(FMUL(va.z,dx2), FMUL(va.w,dy2));
        const float dn = vb.z;
        // sign-exact pre-test for w0>=0 && w1>=0 (no division needed)
        const bool dpos = dn > 0.0f;
        const bool in0 = (num0 == 0.0f) | ((num0 > 0.0f) == dpos);
        const bool in1 = (num1 == 0.0f) | ((num1 > 0.0f) == dpos);
        if (!(in0 && in1)) continue;

        const float w0 = FDIV(num0, dn);
        const float w1 = FDIV(num1, dn);
        const float w2 = FSUB(FSUB(1.0f, w0), w1);
        if (!(w2 >= 0.0f)) continue;

        float cc0 = fminf(fmaxf(w0, 0.0f), 1.0f);
        float cc1 = fminf(fmaxf(w1, 0.0f), 1.0f);
        float cc2 = fminf(fmaxf(w2, 0.0f), 1.0f);
        const float ss = fmaxf(FADD(FADD(cc0,cc1),cc2), 1e-12f);
        cc0 = FDIV(cc0, ss); cc1 = FDIV(cc1, ss); cc2 = FDIV(cc2, ss);

        const float4 vc = s_C[i];
        const float iz = FADD(FADD(FDIV(cc0, vb.w), FDIV(cc1, vc.x)), FDIV(cc2, vc.y));
        const float t  = FADD(iz, 1e-30f);
        const float sg = (t > 0.0f) ? 1.0f : ((t < 0.0f) ? -1.0f : 0.0f);
        const float zp = FMUL(FDIV(1.0f, fmaxf(fabsf(iz), 1e-12f)), sg);

        if (zp > 0.1f && zp < 100.0f && zp < bestz) {
            bestz = zp; besti = i;
            bc0 = cc0; bc1 = cc1; bc2 = cc2; bzp = zp;
        }
    }

    float pr = 0.0f, pg = 0.0f, pb = 0.0f;
    if (besti >= 0) {
        const int i = besti;
        const float4 vb = s_B[i];
        const float4 vc = s_C[i];
        const float zs[3] = { vb.w, vc.x, vc.y };
        const float wc[3] = { bc0, bc1, bc2 };
        int   ti0[3];
        float fr[3];
        #pragma unroll
        for (int k = 0; k < 3; ++k) {
            float v = FMUL(FMUL(wc[k], 3.0f), FDIV(bzp, zs[k]));
            v = fminf(fmaxf(v, 0.0f), 2.999f);
            float fl = floorf(v);
            ti0[k] = (int)fl;
            fr[k]  = FSUB(v, fl);
        }
        const float* tp = tex + (size_t)__float_as_int(vc.z) * 192;  // 4*4*4*3
        #pragma unroll
        for (int corner = 0; corner < 8; ++corner) {
            float w = 1.0f;
            int idx[3];
            #pragma unroll
            for (int k = 0; k < 3; ++k) {
                int bit = (corner >> k) & 1;
                w = FMUL(w, bit ? fr[k] : FSUB(1.0f, fr[k]));
                int id = ti0[k] + bit; if (id > 3) id = 3;
                idx[k] = id;
            }
            const float* tv = tp + (size_t)(((idx[0]*4 + idx[1])*4 + idx[2])*3);
            pr = FADD(pr, FMUL(w, tv[0]));
            pg = FADD(pg, FMUL(w, tv[1]));
            pb = FADD(pb, FMUL(w, tv[2]));
        }
    }

    const int p = row * IMG_S + col;
    out[p]                 = pr;
    out[IMG_S*IMG_S + p]   = pg;
    out[2*IMG_S*IMG_S + p] = pb;
}

extern "C" void kernel_launch(void* const* d_in, const int* in_sizes, int n_in,
                              void* d_out, int out_size, void* d_ws, size_t ws_size,
                              hipStream_t stream) {
    const float* faces = (const float*)d_in[0];   // [1,F,3,3] f32
    const float* tex   = (const float*)d_in[1];   // [1,F,4,4,4,3] f32
    float* out = (float*)d_out;                   // [1,3,256,256] f32
    const int F = in_sizes[0] / 9;                // B=1

    const int grid = (IMG_S / 16) * (IMG_S / 16); // 256 blocks
    raster_kernel<<<grid, 256, 0, stream>>>(faces, tex, out, F);
}

// Round 3
// 10.187 us; speedup vs baseline: 1.2650x; 1.0716x over previous
//
#include <hip/hip_runtime.h>
#include <math.h>
#include <limits.h>

#define IMG_S 256
#define FCAP 256

// Exact-order IEEE f32 helpers (never FMA-contracted)
#define FADD(a,b) __fadd_rn((a),(b))
#define FSUB(a,b) __fsub_rn((a),(b))
#define FMUL(a,b) __fmul_rn((a),(b))
#define FDIV(a,b) __fdiv_rn((a),(b))

__global__ __launch_bounds__(256) void raster_kernel(
    const float* __restrict__ faces,   // [F,3,3]
    const float* __restrict__ tex,     // [F,4,4,4,3]
    float* __restrict__ out,           // [3,S,S]
    int F)
{
    // packed per-face data:
    //   A = (a0, b0, a1, b1)   a0=y1-y2 b0=x2-x1 a1=y2-y0 b1=x0-x2
    //   B = (x2, y2, den, z0)
    //   C = (z1, z2, fid_bits, 0)
    __shared__ float4 s_A[FCAP], s_B[FCAP], s_C[FCAP];
    __shared__ int    s_cnt[4];

    const int tid  = threadIdx.x;
    const int lane = tid & 63;
    const int wid  = tid >> 6;

    // 8x8 pixel tile per block; 4 threads (slots) per pixel
    const int tile_x = blockIdx.x & 31;
    const int tile_y = blockIdx.x >> 5;
    const int col0 = tile_x * 8;
    const int row0 = tile_y * 8;

    // tile NDC pixel-center bounds
    const float px_min = (float)(2*col0       + 1 - IMG_S) / (float)IMG_S;
    const float px_max = (float)(2*(col0+7)   + 1 - IMG_S) / (float)IMG_S;
    const float py_max = -(float)(2*row0      + 1 - IMG_S) / (float)IMG_S;
    const float py_min = -(float)(2*(row0+7)  + 1 - IMG_S) / (float)IMG_S;
    const float MARGIN = 1e-3f;

    // ---- Phase A: cull faces vs tile, ordered compaction into LDS ----
    int nk = 0;
    for (int f0 = 0; f0 < F; f0 += 256) {
        const int f = f0 + tid;
        bool keep = false;
        float x0=0,y0=0,z0=0,x1=0,y1=0,z1=0,x2=0,y2=0,z2=0,den=0.f;
        if (f < F) {
            const float* fp = faces + (size_t)f * 9;
            x0=fp[0]; y0=fp[1]; z0=fp[2];
            x1=fp[3]; y1=fp[4]; z1=fp[5];
            x2=fp[6]; y2=fp[7]; z2=fp[8];
            den = FADD(FMUL(FSUB(y1,y2), FSUB(x0,x2)),
                       FMUL(FSUB(x2,x1), FSUB(y0,y2)));
            float bxmin = fminf(fminf(x0,x1),x2), bxmax = fmaxf(fmaxf(x0,x1),x2);
            float bymin = fminf(fminf(y0,y1),y2), bymax = fmaxf(fmaxf(y0,y1),y2);
            keep = (bxmin - MARGIN <= px_max) && (bxmax + MARGIN >= px_min)
                && (bymin - MARGIN <= py_max) && (bymax + MARGIN >= py_min);
            keep = keep || (fabsf(den) < 1e-9f);   // degenerate safety
        }
        unsigned long long m = __ballot(keep);
        if (lane == 0) s_cnt[wid] = (int)__popcll(m);
        __syncthreads();
        int base = nk;
        #pragma unroll
        for (int w = 0; w < 4; ++w) if (w < wid) base += s_cnt[w];
        if (keep) {
            int pos = base + (int)__popcll(m & ((1ull << lane) - 1ull));
            if (pos < FCAP) {
                float dn = den;
                if (fabsf(dn) < 1e-12f) dn = 1e-12f;  // reference's where()
                s_A[pos] = make_float4(FSUB(y1,y2), FSUB(x2,x1), FSUB(y2,y0), FSUB(x0,x2));
                s_B[pos] = make_float4(x2, y2, dn, z0);
                s_C[pos] = make_float4(z1, z2, __int_as_float(f), 0.0f);
            }
        }
        nk += s_cnt[0] + s_cnt[1] + s_cnt[2] + s_cnt[3];
        __syncthreads();   // s_cnt reuse + LDS visibility
    }
    if (nk > FCAP) nk = FCAP;

    // ---- Phase B: 4 slots per pixel, candidates strided by 4 ----
    const int slot = lane & 3;
    const int pidx = wid * 16 + (lane >> 2);       // 0..63
    const int col = col0 + (pidx & 7);
    const int row = row0 + (pidx >> 3);
    const float px = (float)(2*col + 1 - IMG_S) / (float)IMG_S;
    const float py = -(float)(2*row + 1 - IMG_S) / (float)IMG_S;

    float bestz = INFINITY;
    int   key   = INT_MAX;     // candidate index (face-order); INT_MAX = no hit
    float bc0=0.f, bc1=0.f, bc2=0.f;

    for (int i = slot; i < nk; i += 4) {
        const float4 va = s_A[i];
        const float4 vb = s_B[i];
        const float dx2 = FSUB(px, vb.x);
        const float dy2 = FSUB(py, vb.y);
        const float num0 = FADD(FMUL(va.x,dx2), FMUL(va.y,dy2));
        const float num1 = FADD(FMUL(va.z,dx2), FMUL(va.w,dy2));
        const float dn = vb.z;
        // sign-exact pre-test for w0>=0 && w1>=0 (no division needed)
        const bool dpos = dn > 0.0f;
        const bool in0 = (num0 == 0.0f) | ((num0 > 0.0f) == dpos);
        const bool in1 = (num1 == 0.0f) | ((num1 > 0.0f) == dpos);
        if (!(in0 && in1)) continue;

        const float w0 = FDIV(num0, dn);
        const float w1 = FDIV(num1, dn);
        const float w2 = FSUB(FSUB(1.0f, w0), w1);
        if (!(w2 >= 0.0f)) continue;

        float cc0 = fminf(fmaxf(w0, 0.0f), 1.0f);
        float cc1 = fminf(fmaxf(w1, 0.0f), 1.0f);
        float cc2 = fminf(fmaxf(w2, 0.0f), 1.0f);
        const float ss = fmaxf(FADD(FADD(cc0,cc1),cc2), 1e-12f);
        cc0 = FDIV(cc0, ss); cc1 = FDIV(cc1, ss); cc2 = FDIV(cc2, ss);

        const float4 vc = s_C[i];
        const float iz = FADD(FADD(FDIV(cc0, vb.w), FDIV(cc1, vc.x)), FDIV(cc2, vc.y));
        const float t  = FADD(iz, 1e-30f);
        const float sg = (t > 0.0f) ? 1.0f : ((t < 0.0f) ? -1.0f : 0.0f);
        const float zp = FMUL(FDIV(1.0f, fmaxf(fabsf(iz), 1e-12f)), sg);

        if (zp > 0.1f && zp < 100.0f && zp < bestz) {
            bestz = zp; key = i;
            bc0 = cc0; bc1 = cc1; bc2 = cc2;
        }
    }

    // reduce winner across the 4 slots of this pixel (argmin w/ index tie-break)
    #pragma unroll
    for (int d = 1; d <= 2; d <<= 1) {
        const float oz = __shfl_xor(bestz, d);
        const int   ok = __shfl_xor(key, d);
        const float o0 = __shfl_xor(bc0, d);
        const float o1 = __shfl_xor(bc1, d);
        const float o2 = __shfl_xor(bc2, d);
        const bool take = (oz < bestz) || ((oz == bestz) && (ok < key));
        if (take) { bestz = oz; key = ok; bc0 = o0; bc1 = o1; bc2 = o2; }
    }

    float pr = 0.0f, pg = 0.0f, pb = 0.0f;
    const bool hit = (key != INT_MAX);
    if (hit) {
        const float4 vb = s_B[key];
        const float4 vc = s_C[key];
        const float zs[3] = { vb.w, vc.x, vc.y };
        const float wc[3] = { bc0, bc1, bc2 };
        int   ti0[3];
        float fr[3];
        #pragma unroll
        for (int k = 0; k < 3; ++k) {
            float v = FMUL(FMUL(wc[k], 3.0f), FDIV(bestz, zs[k]));
            v = fminf(fmaxf(v, 0.0f), 2.999f);
            float fl = floorf(v);
            ti0[k] = (int)fl;
            fr[k]  = FSUB(v, fl);
        }
        const float* tp = tex + (size_t)__float_as_int(vc.z) * 192;  // 4*4*4*3
        // this slot handles corners slot*2 and slot*2+1
        #pragma unroll
        for (int c = 0; c < 2; ++c) {
            const int corner = slot * 2 + c;
            float w = 1.0f;
            int idx[3];
            #pragma unroll
            for (int k = 0; k < 3; ++k) {
                int bit = (corner >> k) & 1;
                w = FMUL(w, bit ? fr[k] : FSUB(1.0f, fr[k]));
                int id = ti0[k] + bit; if (id > 3) id = 3;
                idx[k] = id;
            }
            const float* tv = tp + (size_t)(((idx[0]*4 + idx[1])*4 + idx[2])*3);
            pr = FADD(pr, FMUL(w, tv[0]));
            pg = FADD(pg, FMUL(w, tv[1]));
            pb = FADD(pb, FMUL(w, tv[2]));
        }
        // sum corner partials across the 4 slots (all 4 lanes of this pixel in-step)
        #pragma unroll
        for (int d = 1; d <= 2; d <<= 1) {
            pr = FADD(pr, __shfl_xor(pr, d));
            pg = FADD(pg, __shfl_xor(pg, d));
            pb = FADD(pb, __shfl_xor(pb, d));
        }
    }

    if (slot == 0) {
        const int p = row * IMG_S + col;
        out[p]                 = pr;
        out[IMG_S*IMG_S + p]   = pg;
        out[2*IMG_S*IMG_S + p] = pb;
    }
}

extern "C" void kernel_launch(void* const* d_in, const int* in_sizes, int n_in,
                              void* d_out, int out_size, void* d_ws, size_t ws_size,
                              hipStream_t stream) {
    const float* faces = (const float*)d_in[0];   // [1,F,3,3] f32
    const float* tex   = (const float*)d_in[1];   // [1,F,4,4,4,3] f32
    float* out = (float*)d_out;                   // [1,3,256,256] f32
    const int F = in_sizes[0] / 9;                // B=1

    const int grid = (IMG_S / 8) * (IMG_S / 8);   // 32*32 = 1024 blocks
    raster_kernel<<<grid, 256, 0, stream>>>(faces, tex, out, F);
}